// Round 8
// baseline (164.901 us; speedup 1.0000x reference)
//
#include <hip/hip_runtime.h>
#include <cstdint>
#include <cstddef>

#define B_ 2048
#define IN_ 8192
#define O_ 4096
#define K_ 64
#define BP_ (B_ / 2)  // 1024 bf16-pair dwords per xT row

typedef float vfloat4 __attribute__((ext_vector_type(4)));   // clang-native for nt-store
typedef uint32_t vuint2 __attribute__((ext_vector_type(2))); // clang-native for nt-load

// bf16 pair helpers: low 16 bits = even b, high 16 bits = odd b
__device__ __forceinline__ float blo(uint32_t p) { return __uint_as_float(p << 16); }
__device__ __forceinline__ float bhi(uint32_t p) { return __uint_as_float(p & 0xffff0000u); }

// ---------------------------------------------------------------------------
// Kernel 1: transpose + bf16-pack  x[B][IN] f32  ->  xT[IN][BP] u32 (bf16x2)
// ---------------------------------------------------------------------------
__global__ __launch_bounds__(256) void xpose_pack(const float* __restrict__ x,
                                                  uint32_t* __restrict__ xT) {
    __shared__ uint16_t T[64][65];  // 64 i x 64 b tile, +1 pad
    const int t  = threadIdx.x;
    const int b0 = blockIdx.x << 6;   // 32 tiles over B
    const int i0 = blockIdx.y << 6;   // 128 tiles over IN
    const int il = t & 63;
    const int bq = t >> 6;            // 0..3
#pragma unroll
    for (int r = 0; r < 16; ++r) {
        int bl = (bq << 4) + r;
        float v = x[(size_t)(b0 + bl) * IN_ + i0 + il];  // coalesced over il
        uint32_t u = __float_as_uint(v);
        u += 0x7fffu + ((u >> 16) & 1u);                  // round-to-nearest-even
        T[il][bl] = (uint16_t)(u >> 16);
    }
    __syncthreads();
#pragma unroll
    for (int r = 0; r < 8; ++r) {
        int flat = t + (r << 8);
        int iw = flat >> 5;   // 0..63
        int bp = flat & 31;   // 0..31
        uint32_t lo = T[iw][2 * bp];
        uint32_t hi = T[iw][2 * bp + 1];
        __builtin_nontemporal_store(lo | (hi << 16),
                                    &xT[(size_t)(i0 + iw) * BP_ + (b0 >> 1) + bp]);
    }
}

// ---------------------------------------------------------------------------
// Kernel 2: main. Block = 256 threads = 4 waves. Block tile: 256 b x 16 o.
// XCD-aligned: b-tile = f&7 pins each 4 MB xT column slice to one XCD's L2.
// KEY CHANGE vs R7: gathers are NONTEMPORAL (L1 no-allocate streaming).
// The gather stream has ~100% L1 miss rate; R3-R7 showed a hard wall at
// ~1 line/2.9cyc/CU independent of instr rate, occupancy, and MLP depth.
// Theory: TCP allocate+evict per missing line is the toll; nt removes it.
// ---------------------------------------------------------------------------
__global__ __launch_bounds__(256, 8) void spl_main(const uint32_t* __restrict__ xT,
                                                   const int* __restrict__ idx,
                                                   const float* __restrict__ w,
                                                   const float* __restrict__ bias,
                                                   float* __restrict__ out) {
    __shared__ float tile[256][17];  // [b_local][o_local], 17.4 KB
    const int t     = threadIdx.x;
    const int lane  = t & 63;
    const int f     = blockIdx.x;
    const int btile = f & 7;            // == XCD id under round-robin dispatch
    const int otile = f >> 3;           // 0..255
    const int obase = otile << 4;
    const int bbase = btile << 8;
    const int cv    = 2 * lane;         // dword offset within 512B chunk
    const int cbase = bbase >> 1;       // chunk dword base (scalar)
    const int wv    = __builtin_amdgcn_readfirstlane(t >> 6);  // force scalar o

    for (int oi = 0; oi < 4; ++oi) {
        const int o = obase + (wv << 2) + oi;            // uniform per wave
        const int*   ip = idx + o * K_;                  // -> s_load
        const float* wp = w + o * K_;                    // -> s_load
        float a0 = 0.f, a1 = 0.f, a2 = 0.f, a3 = 0.f;
#pragma unroll
        for (int kb = 0; kb < 4; ++kb) {
            // ---- issue 16 independent nt gathers (pinned before any use) ----
            vuint2 q[16];
#pragma unroll
            for (int j = 0; j < 16; ++j) {
                int row = ip[(kb << 4) + j];             // wave-uniform (scalar)
                q[j] = __builtin_nontemporal_load(
                    (const vuint2*)(xT + ((size_t)row << 10) + cbase + cv));
            }
            __builtin_amdgcn_sched_barrier(0);  // no FMA hoisted above the loads
            // ---- consume in issue order (progressive vmcnt drain) ----
#pragma unroll
            for (int j = 0; j < 16; ++j) {
                float wj = wp[(kb << 4) + j];            // wave-uniform (scalar)
                a0 = fmaf(blo(q[j].x), wj, a0);
                a1 = fmaf(bhi(q[j].x), wj, a1);
                a2 = fmaf(blo(q[j].y), wj, a2);
                a3 = fmaf(bhi(q[j].y), wj, a3);
            }
        }
        const float bo = bias[o];
        const int ol = (wv << 2) + oi;
        const int bl0 = 4 * lane;
        tile[bl0 + 0][ol] = a0 + bo;
        tile[bl0 + 1][ol] = a1 + bo;
        tile[bl0 + 2][ol] = a2 + bo;
        tile[bl0 + 3][ol] = a3 + bo;
    }
    __syncthreads();
    // coalesced store: 256 b x 16 o; 4 float4 per thread
    const int bl_ = t >> 2;         // 0..63
    const int ol4 = (t & 3) << 2;   // 0,4,8,12
#pragma unroll
    for (int r = 0; r < 4; ++r) {
        int bl = bl_ + (r << 6);
        vfloat4 v;
        v.x = tile[bl][ol4 + 0];
        v.y = tile[bl][ol4 + 1];
        v.z = tile[bl][ol4 + 2];
        v.w = tile[bl][ol4 + 3];
        __builtin_nontemporal_store(v,
            (vfloat4*)&out[(size_t)(bbase + bl) * O_ + obase + ol4]);
    }
}

// ---------------------------------------------------------------------------
// Fallback (only if workspace is unexpectedly small): correct but slow.
// ---------------------------------------------------------------------------
__global__ __launch_bounds__(256) void spl_naive(const float* __restrict__ x,
                                                 const int* __restrict__ idx,
                                                 const float* __restrict__ w,
                                                 const float* __restrict__ bias,
                                                 float* __restrict__ out) {
    int o = blockIdx.x * 256 + threadIdx.x;
    int b = blockIdx.y;
    const float* xr = x + (size_t)b * IN_;
    float acc = bias[o];
    for (int k = 0; k < K_; ++k)
        acc = fmaf(xr[idx[o * K_ + k]], w[o * K_ + k], acc);
    out[(size_t)b * O_ + o] = acc;
}

extern "C" void kernel_launch(void* const* d_in, const int* in_sizes, int n_in,
                              void* d_out, int out_size, void* d_ws, size_t ws_size,
                              hipStream_t stream) {
    const float* x    = (const float*)d_in[0];
    const int*   idx  = (const int*)d_in[1];
    const float* w    = (const float*)d_in[2];
    const float* bias = (const float*)d_in[3];
    float*       out  = (float*)d_out;

    const size_t xt_bytes = (size_t)IN_ * BP_ * sizeof(uint32_t);  // 32 MiB
    if (ws_size >= xt_bytes) {
        uint32_t* xT = (uint32_t*)d_ws;
        hipLaunchKernelGGL(xpose_pack, dim3(B_ / 64, IN_ / 64), dim3(256), 0, stream, x, xT);
        hipLaunchKernelGGL(spl_main, dim3((O_ / 16) * (B_ / 256)), dim3(256), 0, stream,
                           xT, idx, w, bias, out);
    } else {
        hipLaunchKernelGGL(spl_naive, dim3(O_ / 256, B_), dim3(256), 0, stream,
                           x, idx, w, bias, out);
    }
}

// Round 9
// 80.248 us; speedup vs baseline: 2.0549x; 2.0549x over previous
//
#include <hip/hip_runtime.h>
#include <cstdint>
#include <cstddef>

#define B_ 2048
#define IN_ 8192
#define O_ 4096
#define K_ 64
#define BP_ (B_ / 2)  // 1024 bf16-pair dwords per xT row

typedef float vfloat4 __attribute__((ext_vector_type(4)));  // clang-native for nt-store

// bf16 pair helpers: low 16 bits = even b, high 16 bits = odd b
__device__ __forceinline__ float blo(uint32_t p) { return __uint_as_float(p << 16); }
__device__ __forceinline__ float bhi(uint32_t p) { return __uint_as_float(p & 0xffff0000u); }

// ---------------------------------------------------------------------------
// Kernel 1: transpose + bf16-pack  x[B][IN] f32  ->  xT[IN][BP] u32 (bf16x2)
// ---------------------------------------------------------------------------
__global__ __launch_bounds__(256) void xpose_pack(const float* __restrict__ x,
                                                  uint32_t* __restrict__ xT) {
    __shared__ uint16_t T[64][65];  // 64 i x 64 b tile, +1 pad
    const int t  = threadIdx.x;
    const int b0 = blockIdx.x << 6;   // 32 tiles over B
    const int i0 = blockIdx.y << 6;   // 128 tiles over IN
    const int il = t & 63;
    const int bq = t >> 6;            // 0..3
#pragma unroll
    for (int r = 0; r < 16; ++r) {
        int bl = (bq << 4) + r;
        float v = x[(size_t)(b0 + bl) * IN_ + i0 + il];  // coalesced over il
        uint32_t u = __float_as_uint(v);
        u += 0x7fffu + ((u >> 16) & 1u);                  // round-to-nearest-even
        T[il][bl] = (uint16_t)(u >> 16);
    }
    __syncthreads();
#pragma unroll
    for (int r = 0; r < 8; ++r) {
        int flat = t + (r << 8);
        int iw = flat >> 5;   // 0..63
        int bp = flat & 31;   // 0..31
        uint32_t lo = T[iw][2 * bp];
        uint32_t hi = T[iw][2 * bp + 1];
        __builtin_nontemporal_store(lo | (hi << 16),
                                    &xT[(size_t)(i0 + iw) * BP_ + (b0 >> 1) + bp]);
    }
}

// ---------------------------------------------------------------------------
// Kernel 2: main. Block = 256 threads = 4 waves. Block tile: 256 b x 16 o.
// XCD-aligned: b-tile = f&7 pins each 4 MB xT column slice to one XCD's L2.
// KEY CHANGE vs R7 (R8's nt-load reverted: it bypassed L2, FETCH 3x, +50%):
// lane-split dwordx4 gathers. One wave-load = TWO rows' 512B chunks
// (lanes 0-31 -> row r0, lanes 32-63 -> r1, 16B/lane). Wave-load count
// halves; bytes/lines identical -> isolates request-rate vs line-rate wall.
// Even/odd-row partials live in opposite wave halves; combined at the end
// via __shfl_xor(.,32).
// ---------------------------------------------------------------------------
__global__ __launch_bounds__(256, 4) void spl_main(const uint32_t* __restrict__ xT,
                                                   const int* __restrict__ idx,
                                                   const float* __restrict__ w,
                                                   const float* __restrict__ bias,
                                                   float* __restrict__ out) {
    __shared__ float tile[256][17];  // [b_local][o_local], 17.4 KB
    const int t     = threadIdx.x;
    const int lane  = t & 63;
    const int half  = lane >> 5;        // 0: even-slot rows, 1: odd-slot rows
    const int l5    = lane & 31;
    const int f     = blockIdx.x;
    const int btile = f & 7;            // == XCD id under round-robin dispatch
    const int otile = f >> 3;           // 0..255
    const int obase = otile << 4;
    const int bbase = btile << 8;
    const int cbase = bbase >> 1;       // chunk dword base (scalar)
    const int wv    = __builtin_amdgcn_readfirstlane(t >> 6);  // force scalar o

    for (int oi = 0; oi < 4; ++oi) {
        const int o = obase + (wv << 2) + oi;            // uniform per wave
        const int*   ip = idx + o * K_;                  // -> s_load
        const float* wp = w + o * K_;                    // -> s_load
        float a0 = 0.f, a1 = 0.f, a2 = 0.f, a3 = 0.f;
        float a4 = 0.f, a5 = 0.f, a6 = 0.f, a7 = 0.f;
#pragma unroll
        for (int kb = 0; kb < 4; ++kb) {
            // ---- issue 8 dwordx4 gathers covering 16 rows ----
            uint4 q[8];
            float ws[8];
#pragma unroll
            for (int j = 0; j < 8; ++j) {
                int k2 = (kb << 4) + 2 * j;
                int r0 = ip[k2];                         // wave-uniform (scalar)
                int r1 = ip[k2 + 1];
                const uint32_t* p0 = xT + ((size_t)r0 << 10) + cbase;
                const uint32_t* p1 = xT + ((size_t)r1 << 10) + cbase;
                const uint32_t* ps = half ? p1 : p0;     // v_cndmask on base
                q[j]  = *(const uint4*)(ps + (l5 << 2)); // 16B/lane, 1024B/wave
                ws[j] = half ? wp[k2 + 1] : wp[k2];
            }
            __builtin_amdgcn_sched_barrier(0);  // no FMA hoisted above the loads
            // ---- consume in issue order (progressive vmcnt drain) ----
#pragma unroll
            for (int j = 0; j < 8; ++j) {
                float wj = ws[j];
                a0 = fmaf(blo(q[j].x), wj, a0);
                a1 = fmaf(bhi(q[j].x), wj, a1);
                a2 = fmaf(blo(q[j].y), wj, a2);
                a3 = fmaf(bhi(q[j].y), wj, a3);
                a4 = fmaf(blo(q[j].z), wj, a4);
                a5 = fmaf(bhi(q[j].z), wj, a5);
                a6 = fmaf(blo(q[j].w), wj, a6);
                a7 = fmaf(bhi(q[j].w), wj, a7);
            }
        }
        // combine even-row half (lanes 0-31) with odd-row half (lanes 32-63);
        // lane l5 owns b = bbase + 8*l5 .. 8*l5+7
        const float bo = bias[o];
        const int ol = (wv << 2) + oi;
        float s0 = a0 + __shfl_xor(a0, 32, 64);
        float s1 = a1 + __shfl_xor(a1, 32, 64);
        float s2 = a2 + __shfl_xor(a2, 32, 64);
        float s3 = a3 + __shfl_xor(a3, 32, 64);
        float s4 = a4 + __shfl_xor(a4, 32, 64);
        float s5 = a5 + __shfl_xor(a5, 32, 64);
        float s6 = a6 + __shfl_xor(a6, 32, 64);
        float s7 = a7 + __shfl_xor(a7, 32, 64);
        if (half == 0) {
            const int bl0 = l5 << 3;
            tile[bl0 + 0][ol] = s0 + bo;
            tile[bl0 + 1][ol] = s1 + bo;
            tile[bl0 + 2][ol] = s2 + bo;
            tile[bl0 + 3][ol] = s3 + bo;
            tile[bl0 + 4][ol] = s4 + bo;
            tile[bl0 + 5][ol] = s5 + bo;
            tile[bl0 + 6][ol] = s6 + bo;
            tile[bl0 + 7][ol] = s7 + bo;
        }
    }
    __syncthreads();
    // coalesced store: 256 b x 16 o; 4 float4 per thread
    const int bl_ = t >> 2;         // 0..63
    const int ol4 = (t & 3) << 2;   // 0,4,8,12
#pragma unroll
    for (int r = 0; r < 4; ++r) {
        int bl = bl_ + (r << 6);
        vfloat4 v;
        v.x = tile[bl][ol4 + 0];
        v.y = tile[bl][ol4 + 1];
        v.z = tile[bl][ol4 + 2];
        v.w = tile[bl][ol4 + 3];
        __builtin_nontemporal_store(v,
            (vfloat4*)&out[(size_t)(bbase + bl) * O_ + obase + ol4]);
    }
}

// ---------------------------------------------------------------------------
// Fallback (only if workspace is unexpectedly small): correct but slow.
// ---------------------------------------------------------------------------
__global__ __launch_bounds__(256) void spl_naive(const float* __restrict__ x,
                                                 const int* __restrict__ idx,
                                                 const float* __restrict__ w,
                                                 const float* __restrict__ bias,
                                                 float* __restrict__ out) {
    int o = blockIdx.x * 256 + threadIdx.x;
    int b = blockIdx.y;
    const float* xr = x + (size_t)b * IN_;
    float acc = bias[o];
    for (int k = 0; k < K_; ++k)
        acc = fmaf(xr[idx[o * K_ + k]], w[o * K_ + k], acc);
    out[(size_t)b * O_ + o] = acc;
}

extern "C" void kernel_launch(void* const* d_in, const int* in_sizes, int n_in,
                              void* d_out, int out_size, void* d_ws, size_t ws_size,
                              hipStream_t stream) {
    const float* x    = (const float*)d_in[0];
    const int*   idx  = (const int*)d_in[1];
    const float* w    = (const float*)d_in[2];
    const float* bias = (const float*)d_in[3];
    float*       out  = (float*)d_out;

    const size_t xt_bytes = (size_t)IN_ * BP_ * sizeof(uint32_t);  // 32 MiB
    if (ws_size >= xt_bytes) {
        uint32_t* xT = (uint32_t*)d_ws;
        hipLaunchKernelGGL(xpose_pack, dim3(B_ / 64, IN_ / 64), dim3(256), 0, stream, x, xT);
        hipLaunchKernelGGL(spl_main, dim3((O_ / 16) * (B_ / 256)), dim3(256), 0, stream,
                           xT, idx, w, bias, out);
    } else {
        hipLaunchKernelGGL(spl_naive, dim3(O_ / 256, B_), dim3(256), 0, stream,
                           x, idx, w, bias, out);
    }
}